// Round 2
// baseline (394.779 us; speedup 1.0000x reference)
//
#include <hip/hip_runtime.h>
#include <hip/hip_bf16.h>

typedef __hip_bfloat16 bf16;
typedef __attribute__((ext_vector_type(4))) float f32x4;
typedef __attribute__((ext_vector_type(8))) short s16x8;
typedef __attribute__((ext_vector_type(4))) short s16x4;

#define B_    4
#define S_    2048
#define H_    16
#define HD_   64
#define DIN   1024
#define DOUT  1024

__device__ __forceinline__ void gld16(const void* g, void* l) {
  __builtin_amdgcn_global_load_lds((const __attribute__((address_space(1))) void*)g,
                                   (__attribute__((address_space(3))) void*)l, 16, 0, 0);
}

__device__ __forceinline__ short bfbits(float f) {
  bf16 h = __float2bfloat16(f);
  short r; __builtin_memcpy(&r, &h, 2); return r;
}

// ---------------- convert x (f32) -> bf16 ----------------
__global__ __launch_bounds__(256) void cvt_f32_bf16(const float* __restrict__ in,
                                                    bf16* __restrict__ out, int n4) {
  int i = blockIdx.x * 256 + threadIdx.x;
  if (i >= n4) return;
  float4 v = reinterpret_cast<const float4*>(in)[i];
  s16x4 o = { bfbits(v.x), bfbits(v.y), bfbits(v.z), bfbits(v.w) };
  reinterpret_cast<s16x4*>(out)[i] = o;
}

// ---------------- W[k][n] f32 -> Wt[n][k] bf16 (z selects matrix) ----------------
__global__ __launch_bounds__(256) void transpose_w_bf16(
    const float* __restrict__ W0, const float* __restrict__ W1,
    const float* __restrict__ W2, const float* __restrict__ W3,
    bf16* __restrict__ T0, bf16* __restrict__ T1,
    bf16* __restrict__ T2, bf16* __restrict__ T3) {
  const float* W; bf16* T;
  switch (blockIdx.z) {
    case 0:  W = W0; T = T0; break;
    case 1:  W = W1; T = T1; break;
    case 2:  W = W2; T = T2; break;
    default: W = W3; T = T3; break;
  }
  __shared__ float tile[32][33];
  const int n0 = blockIdx.x * 32, k0 = blockIdx.y * 32;
  const int tx = threadIdx.x & 31, ty = threadIdx.x >> 5;
#pragma unroll
  for (int i = 0; i < 4; ++i)
    tile[ty + i * 8][tx] = W[(size_t)(k0 + ty + i * 8) * DOUT + n0 + tx];
  __syncthreads();
#pragma unroll
  for (int i = 0; i < 4; ++i)
    T[(size_t)(n0 + ty + i * 8) * DIN + k0 + tx] = __float2bfloat16(tile[tx][ty + i * 8]);
}

// ---------------- shared 128x128 GEMM mainloop (m97 structure) ----------------
// A row-major [M][K], Bt row-major [N][K], both bf16. BK=32.
template <int KDIM>
__device__ __forceinline__ void gemm128_mainloop(
    const bf16* __restrict__ A, const bf16* __restrict__ Bt,
    int brow, int bcol, bf16* Al, bf16* Bl, f32x4 acc[4][4]) {
  const int tid = threadIdx.x;
  const int lane = tid & 63;
  const int wr = (tid >> 6) >> 1, wc = (tid >> 6) & 1;
  const int lq = lane & 15, lg = lane >> 4;
  const int r0 = tid >> 2, kg = tid & 3;   // chunk c=tid: row=c/4, kgrp=c&3 (8 bf16)

  for (int k0 = 0; k0 < KDIM; k0 += 32) {
    gld16(A  + (size_t)(brow + r0)      * KDIM + k0 + kg * 8, (char*)Al + tid * 16);
    gld16(A  + (size_t)(brow + r0 + 64) * KDIM + k0 + kg * 8, (char*)Al + (tid + 256) * 16);
    gld16(Bt + (size_t)(bcol + r0)      * KDIM + k0 + kg * 8, (char*)Bl + tid * 16);
    gld16(Bt + (size_t)(bcol + r0 + 64) * KDIM + k0 + kg * 8, (char*)Bl + (tid + 256) * 16);
    __syncthreads();
    s16x8 af[4], bff[4];
#pragma unroll
    for (int m = 0; m < 4; ++m)
      af[m] = *(const s16x8*)((const char*)Al + (wr * 64 + m * 16 + lq) * 64 + lg * 16);
#pragma unroll
    for (int n = 0; n < 4; ++n)
      bff[n] = *(const s16x8*)((const char*)Bl + (wc * 64 + n * 16 + lq) * 64 + lg * 16);
#pragma unroll
    for (int m = 0; m < 4; ++m)
#pragma unroll
      for (int n = 0; n < 4; ++n)
        acc[m][n] = __builtin_amdgcn_mfma_f32_16x16x32_bf16(af[m], bff[n], acc[m][n], 0, 0, 0);
    __syncthreads();
  }
}

// ---------------- QKV projection: out scattered to [b][h][s][hd], Q scaled 0.125 ----------------
__global__ __launch_bounds__(256) void gemm_qkv(
    const bf16* __restrict__ A,
    const bf16* __restrict__ Wqt, const bf16* __restrict__ Wkt, const bf16* __restrict__ Wvt,
    bf16* __restrict__ Qo, bf16* __restrict__ Ko, bf16* __restrict__ Vo) {
  __shared__ alignas(16) bf16 Al[128 * 32];
  __shared__ alignas(16) bf16 Bl[128 * 32];
  const int z = blockIdx.z;
  const bf16* Bt = (z == 0) ? Wqt : (z == 1) ? Wkt : Wvt;
  bf16* Out = (z == 0) ? Qo : (z == 1) ? Ko : Vo;
  const float scale = (z == 0) ? 0.125f : 1.0f;   // fold 1/sqrt(64) into Q
  const int brow = blockIdx.x * 128, bcol = blockIdx.y * 128;
  f32x4 acc[4][4];
  const f32x4 z4 = {0.f, 0.f, 0.f, 0.f};
#pragma unroll
  for (int m = 0; m < 4; ++m)
#pragma unroll
    for (int n = 0; n < 4; ++n) acc[m][n] = z4;
  gemm128_mainloop<1024>(A, Bt, brow, bcol, Al, Bl, acc);
  const int lane = threadIdx.x & 63;
  const int wr = (threadIdx.x >> 6) >> 1, wc = (threadIdx.x >> 6) & 1;
  const int lq = lane & 15, lg = lane >> 4;
#pragma unroll
  for (int m = 0; m < 4; ++m) {
#pragma unroll
    for (int n = 0; n < 4; ++n) {
      const int col = bcol + wc * 64 + n * 16 + lq;
      const int h = col >> 6, hd = col & 63;
#pragma unroll
      for (int r = 0; r < 4; ++r) {
        const int row = brow + wr * 64 + m * 16 + lg * 4 + r;  // C/D: row=(lane>>4)*4+reg
        const int b = row >> 11, s = row & 2047;
        Out[(((size_t)(b * H_ + h) * S_ + s) << 6) + hd] = __float2bfloat16(acc[m][n][r] * scale);
      }
    }
  }
}

// ---------------- flash attention, causal. QT=64 KT=128, 4 waves x 16 q-rows ----------------
__global__ __launch_bounds__(256) void attn_fwd(
    const bf16* __restrict__ Qg, const bf16* __restrict__ Kg, const bf16* __restrict__ Vg,
    bf16* __restrict__ ctx) {
  __shared__ alignas(16) bf16 Ks[128 * 64];       // logical [key][hd], phys ^((key&7)<<4)
  __shared__ alignas(16) bf16 Vt[64 * 128];       // logical [hd][key], phys ^((hd&15)<<4)
  __shared__ alignas(16) bf16 Ps[4][16 * 128];    // per-wave [q][key],  phys ^((q&15)<<4)
  const int qi = blockIdx.x, bh = blockIdx.y;
  const int tid = threadIdx.x, wave = tid >> 6, lane = tid & 63;
  const int lq = lane & 15, lg = lane >> 4;
  const size_t base = (size_t)bh * S_ * HD_;
  const int qt0 = qi * 64;
  const int qw0 = qt0 + wave * 16;

  // Q fragments in registers (pre-scaled by 0.125 in gemm_qkv)
  s16x8 qf[2];
  {
    const bf16* qp = Qg + base + (size_t)(qw0 + lq) * HD_ + lg * 8;
    qf[0] = *(const s16x8*)qp;
    qf[1] = *(const s16x8*)(qp + 32);
  }
  const f32x4 z4 = {0.f, 0.f, 0.f, 0.f};
  f32x4 o[4];
#pragma unroll
  for (int nf = 0; nf < 4; ++nf) o[nf] = z4;
  float mrow[4] = {-1e30f, -1e30f, -1e30f, -1e30f};
  float lrow[4] = {0.f, 0.f, 0.f, 0.f};

  const int n_kv = (qt0 + 63) / 128 + 1;
  for (int kt = 0; kt < n_kv; ++kt) {
    const int k0 = kt * 128;
    // stage K: global_load_lds, linear LDS dest + inverse-swizzled global source (rule #21)
#pragma unroll
    for (int i = 0; i < 4; ++i) {
      const int c = tid + i * 256;
      const int key = c >> 3;
      const int s8 = (c & 7) ^ (key & 7);
      gld16(Kg + base + (size_t)(k0 + key) * HD_ + s8 * 8, (char*)Ks + c * 16);
    }
    // stage V transposed via regs: 4 keys x 8 hd per thread -> 8x ds_write_b64
    {
      const int key0 = (tid & 31) * 4, hdg = tid >> 5;
      const bf16* vp = Vg + base + (size_t)(k0 + key0) * HD_ + hdg * 8;
      s16x8 v0 = *(const s16x8*)vp;
      s16x8 v1 = *(const s16x8*)(vp + HD_);
      s16x8 v2 = *(const s16x8*)(vp + 2 * HD_);
      s16x8 v3 = *(const s16x8*)(vp + 3 * HD_);
#pragma unroll
      for (int j = 0; j < 8; ++j) {
        const int hd = hdg * 8 + j;
        const int byte = ((hd * 128 + key0) * 2) ^ ((hd & 15) << 4);
        s16x4 wv = { v0[j], v1[j], v2[j], v3[j] };
        *(s16x4*)((char*)Vt + byte) = wv;
      }
    }
    __syncthreads();

    // QK^T: C[q][key], A=Q frags, B: lane holds K[key=n*16+lq][hd contiguous]
    f32x4 sc[8];
#pragma unroll
    for (int n = 0; n < 8; ++n) sc[n] = z4;
#pragma unroll
    for (int ks = 0; ks < 2; ++ks) {
#pragma unroll
      for (int n = 0; n < 8; ++n) {
        const int key = n * 16 + lq;
        const int byte = (key * 128 + ks * 64 + lg * 16) ^ ((key & 7) << 4);
        const s16x8 kf = *(const s16x8*)((const char*)Ks + byte);
        sc[n] = __builtin_amdgcn_mfma_f32_16x16x32_bf16(qf[ks], kf, sc[n], 0, 0, 0);
      }
    }
    // causal mask (exact per-wave condition)
    if (k0 + 127 > qw0) {
#pragma unroll
      for (int n = 0; n < 8; ++n) {
        const int gk = k0 + n * 16 + lq;
#pragma unroll
        for (int r = 0; r < 4; ++r) {
          const int gq = qw0 + lg * 4 + r;
          if (gk > gq) sc[n][r] = -1e30f;
        }
      }
    }
    // online softmax: rows live in 16-lane groups (lanes sharing lane>>4)
    float alpha[4];
#pragma unroll
    for (int r = 0; r < 4; ++r) {
      float mx = sc[0][r];
#pragma unroll
      for (int n = 1; n < 8; ++n) mx = fmaxf(mx, sc[n][r]);
#pragma unroll
      for (int msk = 1; msk < 16; msk <<= 1) mx = fmaxf(mx, __shfl_xor(mx, msk, 64));
      const float mnew = fmaxf(mrow[r], mx);
      alpha[r] = __expf(mrow[r] - mnew);
      mrow[r] = mnew;
    }
    float rs[4] = {0.f, 0.f, 0.f, 0.f};
#pragma unroll
    for (int n = 0; n < 8; ++n)
#pragma unroll
      for (int r = 0; r < 4; ++r) {
        const float p = __expf(sc[n][r] - mrow[r]);
        sc[n][r] = p;
        rs[r] += p;
      }
#pragma unroll
    for (int r = 0; r < 4; ++r) {
#pragma unroll
      for (int msk = 1; msk < 16; msk <<= 1) rs[r] += __shfl_xor(rs[r], msk, 64);
      lrow[r] = lrow[r] * alpha[r] + rs[r];
    }
    // P -> per-wave LDS (C-layout write, A-layout read; same-wave, no barrier needed)
    char* psb = (char*)&Ps[wave][0];
#pragma unroll
    for (int n = 0; n < 8; ++n)
#pragma unroll
      for (int r = 0; r < 4; ++r) {
        const int q = lg * 4 + r;
        const int byte = ((q * 128 + (n * 16 + lq)) * 2) ^ ((q & 15) << 4);
        *(bf16*)(psb + byte) = __float2bfloat16(sc[n][r]);
      }
#pragma unroll
    for (int nf = 0; nf < 4; ++nf)
#pragma unroll
      for (int r = 0; r < 4; ++r) o[nf][r] *= alpha[r];
    // PV: C[q][hd] += P[q][key] * V[key][hd]
#pragma unroll
    for (int ks = 0; ks < 4; ++ks) {
      const int abyte = ((lq * 128 + ks * 32 + lg * 8) * 2) ^ ((lq & 15) << 4);
      const s16x8 pf = *(const s16x8*)(psb + abyte);
#pragma unroll
      for (int nf = 0; nf < 4; ++nf) {
        const int hd = nf * 16 + lq;
        const int bbyte = ((hd * 128 + ks * 32 + lg * 8) * 2) ^ ((hd & 15) << 4);
        const s16x8 vf = *(const s16x8*)((const char*)Vt + bbyte);
        o[nf] = __builtin_amdgcn_mfma_f32_16x16x32_bf16(pf, vf, o[nf], 0, 0, 0);
      }
    }
    __syncthreads();
  }
  // epilogue: ctx[b][s][h*64+hd] bf16
  const int b = bh >> 4, h = bh & 15;
#pragma unroll
  for (int nf = 0; nf < 4; ++nf)
#pragma unroll
    for (int r = 0; r < 4; ++r) {
      const int s = qw0 + lg * 4 + r;
      ctx[(size_t)(b * S_ + s) * DOUT + h * HD_ + nf * 16 + lq] =
          __float2bfloat16(o[nf][r] / lrow[r]);
    }
}

// ---------------- output projection + bias, FLOAT32 out (reference output dtype) ----------------
__global__ __launch_bounds__(256) void gemm_outproj(
    const bf16* __restrict__ A, const bf16* __restrict__ Wot,
    const float* __restrict__ bo, float* __restrict__ out) {
  __shared__ alignas(16) bf16 Al[128 * 32];
  __shared__ alignas(16) bf16 Bl[128 * 32];
  const int brow = blockIdx.x * 128, bcol = blockIdx.y * 128;
  f32x4 acc[4][4];
  const f32x4 z4 = {0.f, 0.f, 0.f, 0.f};
#pragma unroll
  for (int m = 0; m < 4; ++m)
#pragma unroll
    for (int n = 0; n < 4; ++n) acc[m][n] = z4;
  gemm128_mainloop<1024>(A, Wot, brow, bcol, Al, Bl, acc);
  const int lane = threadIdx.x & 63;
  const int wr = (threadIdx.x >> 6) >> 1, wc = (threadIdx.x >> 6) & 1;
  const int lq = lane & 15, lg = lane >> 4;
#pragma unroll
  for (int m = 0; m < 4; ++m) {
#pragma unroll
    for (int n = 0; n < 4; ++n) {
      const int col = bcol + wc * 64 + n * 16 + lq;
      const float bias = bo[col];
#pragma unroll
      for (int r = 0; r < 4; ++r) {
        const int row = brow + wr * 64 + m * 16 + lg * 4 + r;
        out[(size_t)row * DOUT + col] = acc[m][n][r] + bias;
      }
    }
  }
}

extern "C" void kernel_launch(void* const* d_in, const int* in_sizes, int n_in,
                              void* d_out, int out_size, void* d_ws, size_t ws_size,
                              hipStream_t stream) {
  (void)in_sizes; (void)n_in; (void)out_size; (void)ws_size;
  const float* x  = (const float*)d_in[0];
  const float* Wq = (const float*)d_in[1];
  const float* Wk = (const float*)d_in[2];
  const float* Wv = (const float*)d_in[3];
  const float* Wo = (const float*)d_in[4];
  const float* bo = (const float*)d_in[5];
  float* out = (float*)d_out;   // reference output dtype is float32

  char* ws = (char*)d_ws;
  // workspace map (88 MB total)
  bf16* xb  = (bf16*)(ws);                                  // 16 MB: x bf16 [8192][1024]
  bf16* Wqt = (bf16*)(ws + (16u << 20));                    //  2 MB each: Wt[n][k]
  bf16* Wkt = (bf16*)(ws + (18u << 20));
  bf16* Wvt = (bf16*)(ws + (20u << 20));
  bf16* Wot = (bf16*)(ws + (22u << 20));
  bf16* Qb  = (bf16*)(ws + (24u << 20));                    // 16 MB: [b][h][s][hd]
  bf16* Kb  = (bf16*)(ws + (40u << 20));
  bf16* Vb  = (bf16*)(ws + (56u << 20));
  bf16* ctx = (bf16*)(ws + (72u << 20));                    // 16 MB: [b][s][h*64+hd]

  cvt_f32_bf16<<<dim3(8192), dim3(256), 0, stream>>>(x, xb, (B_ * S_ * DIN) / 4);
  transpose_w_bf16<<<dim3(32, 32, 4), dim3(256), 0, stream>>>(Wq, Wk, Wv, Wo,
                                                              Wqt, Wkt, Wvt, Wot);
  gemm_qkv<<<dim3(64, 8, 3), dim3(256), 0, stream>>>(xb, Wqt, Wkt, Wvt, Qb, Kb, Vb);
  attn_fwd<<<dim3(32, 64), dim3(256), 0, stream>>>(Qb, Kb, Vb, ctx);
  gemm_outproj<<<dim3(64, 8), dim3(256), 0, stream>>>(ctx, Wot, bo, out);
}

// Round 3
// 307.964 us; speedup vs baseline: 1.2819x; 1.2819x over previous
//
#include <hip/hip_runtime.h>
#include <hip/hip_bf16.h>

typedef __hip_bfloat16 bf16;
typedef __attribute__((ext_vector_type(4))) float f32x4;
typedef __attribute__((ext_vector_type(8))) short s16x8;
typedef __attribute__((ext_vector_type(4))) short s16x4;
typedef __attribute__((ext_vector_type(4))) unsigned int u32x4;

#define B_    4
#define S_    2048
#define H_    16
#define HD_   64
#define DIN   1024
#define DOUT  1024

__device__ __forceinline__ void gld16(const void* g, void* l) {
  __builtin_amdgcn_global_load_lds((const __attribute__((address_space(1))) void*)g,
                                   (__attribute__((address_space(3))) void*)l, 16, 0, 0);
}

__device__ __forceinline__ short bfbits(float f) {
  bf16 h = __float2bfloat16(f);
  short r; __builtin_memcpy(&r, &h, 2); return r;
}

__device__ __forceinline__ unsigned pk2(float lo, float hi) {
  return (unsigned)(unsigned short)bfbits(lo) | ((unsigned)(unsigned short)bfbits(hi) << 16);
}

// ---------------- convert x (f32) -> bf16 ----------------
__global__ __launch_bounds__(256) void cvt_f32_bf16(const float* __restrict__ in,
                                                    bf16* __restrict__ out, int n4) {
  int i = blockIdx.x * 256 + threadIdx.x;
  if (i >= n4) return;
  float4 v = reinterpret_cast<const float4*>(in)[i];
  s16x4 o = { bfbits(v.x), bfbits(v.y), bfbits(v.z), bfbits(v.w) };
  reinterpret_cast<s16x4*>(out)[i] = o;
}

// ---------------- W[k][n] f32 -> Wt[n][k] bf16 (z selects matrix) ----------------
__global__ __launch_bounds__(256) void transpose_w_bf16(
    const float* __restrict__ W0, const float* __restrict__ W1,
    const float* __restrict__ W2, const float* __restrict__ W3,
    bf16* __restrict__ T0, bf16* __restrict__ T1,
    bf16* __restrict__ T2, bf16* __restrict__ T3) {
  const float* W; bf16* T;
  switch (blockIdx.z) {
    case 0:  W = W0; T = T0; break;
    case 1:  W = W1; T = T1; break;
    case 2:  W = W2; T = T2; break;
    default: W = W3; T = T3; break;
  }
  __shared__ float tile[32][33];
  const int n0 = blockIdx.x * 32, k0 = blockIdx.y * 32;
  const int tx = threadIdx.x & 31, ty = threadIdx.x >> 5;
#pragma unroll
  for (int i = 0; i < 4; ++i)
    tile[ty + i * 8][tx] = W[(size_t)(k0 + ty + i * 8) * DOUT + n0 + tx];
  __syncthreads();
#pragma unroll
  for (int i = 0; i < 4; ++i)
    T[(size_t)(n0 + ty + i * 8) * DIN + k0 + tx] = __float2bfloat16(tile[tx][ty + i * 8]);
}

// ---------------- shared 128x128 GEMM mainloop (m97 structure) ----------------
template <int KDIM>
__device__ __forceinline__ void gemm128_mainloop(
    const bf16* __restrict__ A, const bf16* __restrict__ Bt,
    int brow, int bcol, bf16* Al, bf16* Bl, f32x4 acc[4][4]) {
  const int tid = threadIdx.x;
  const int lane = tid & 63;
  const int wr = (tid >> 6) >> 1, wc = (tid >> 6) & 1;
  const int lq = lane & 15, lg = lane >> 4;
  const int r0 = tid >> 2, kg = tid & 3;

  for (int k0 = 0; k0 < KDIM; k0 += 32) {
    gld16(A  + (size_t)(brow + r0)      * KDIM + k0 + kg * 8, (char*)Al + tid * 16);
    gld16(A  + (size_t)(brow + r0 + 64) * KDIM + k0 + kg * 8, (char*)Al + (tid + 256) * 16);
    gld16(Bt + (size_t)(bcol + r0)      * KDIM + k0 + kg * 8, (char*)Bl + tid * 16);
    gld16(Bt + (size_t)(bcol + r0 + 64) * KDIM + k0 + kg * 8, (char*)Bl + (tid + 256) * 16);
    __syncthreads();
    s16x8 af[4], bff[4];
#pragma unroll
    for (int m = 0; m < 4; ++m)
      af[m] = *(const s16x8*)((const char*)Al + (wr * 64 + m * 16 + lq) * 64 + lg * 16);
#pragma unroll
    for (int n = 0; n < 4; ++n)
      bff[n] = *(const s16x8*)((const char*)Bl + (wc * 64 + n * 16 + lq) * 64 + lg * 16);
#pragma unroll
    for (int m = 0; m < 4; ++m)
#pragma unroll
      for (int n = 0; n < 4; ++n)
        acc[m][n] = __builtin_amdgcn_mfma_f32_16x16x32_bf16(af[m], bff[n], acc[m][n], 0, 0, 0);
    __syncthreads();
  }
}

// ---------------- QKV projection: out scattered to [b][h][s][hd], Q scaled 0.125 ----------------
__global__ __launch_bounds__(256) void gemm_qkv(
    const bf16* __restrict__ A,
    const bf16* __restrict__ Wqt, const bf16* __restrict__ Wkt, const bf16* __restrict__ Wvt,
    bf16* __restrict__ Qo, bf16* __restrict__ Ko, bf16* __restrict__ Vo) {
  __shared__ alignas(16) bf16 Al[128 * 32];
  __shared__ alignas(16) bf16 Bl[128 * 32];
  const int z = blockIdx.z;
  const bf16* Bt = (z == 0) ? Wqt : (z == 1) ? Wkt : Wvt;
  bf16* Out = (z == 0) ? Qo : (z == 1) ? Ko : Vo;
  const float scale = (z == 0) ? 0.125f : 1.0f;
  const int brow = blockIdx.x * 128, bcol = blockIdx.y * 128;
  f32x4 acc[4][4];
  const f32x4 z4 = {0.f, 0.f, 0.f, 0.f};
#pragma unroll
  for (int m = 0; m < 4; ++m)
#pragma unroll
    for (int n = 0; n < 4; ++n) acc[m][n] = z4;
  gemm128_mainloop<1024>(A, Bt, brow, bcol, Al, Bl, acc);
  const int lane = threadIdx.x & 63;
  const int wr = (threadIdx.x >> 6) >> 1, wc = (threadIdx.x >> 6) & 1;
  const int lq = lane & 15, lg = lane >> 4;
#pragma unroll
  for (int m = 0; m < 4; ++m) {
#pragma unroll
    for (int n = 0; n < 4; ++n) {
      const int col = bcol + wc * 64 + n * 16 + lq;
      const int h = col >> 6, hd = col & 63;
#pragma unroll
      for (int r = 0; r < 4; ++r) {
        const int row = brow + wr * 64 + m * 16 + lg * 4 + r;
        const int b = row >> 11, s = row & 2047;
        Out[(((size_t)(b * H_ + h) * S_ + s) << 6) + hd] = __float2bfloat16(acc[m][n][r] * scale);
      }
    }
  }
}

// ---------------- flash attention, causal. QT=64 KT=128, 4 waves x 16 q-rows ----------------
// Swapped QK^T: mfma(K,Q) -> lane holds P^T[:, q=lq]; softmax fully in-register;
// P redistributed to PV B-operand layout via ds_bpermute (no P LDS round-trip).
// PV computes O^T with Vt as A-operand. LDS 32KB -> 4-5 blocks/CU.
__global__ __launch_bounds__(256, 4) void attn_fwd(
    const bf16* __restrict__ Qg, const bf16* __restrict__ Kg, const bf16* __restrict__ Vg,
    bf16* __restrict__ ctx) {
  __shared__ alignas(16) bf16 Ks[128 * 64];       // logical [key][hd], phys ^((key&7)<<4)
  __shared__ alignas(16) bf16 Vt[64 * 128];       // logical [hd][key], phys ^((hd&15)<<4)
  // bijective XCD swizzle: each XCD's L2 gets 8 contiguous bh (8 x 512KB = 4MB = L2)
  const int orig = blockIdx.y * 32 + blockIdx.x;          // 2048 blocks, x fastest
  const int sw = ((orig & 7) << 8) | (orig >> 3);
  const int qi = sw & 31, bh = sw >> 5;
  const int tid = threadIdx.x, wave = tid >> 6, lane = tid & 63;
  const int lq = lane & 15, lg = lane >> 4;
  const size_t base = (size_t)bh * S_ * HD_;
  const int qt0 = qi * 64;
  const int qw0 = qt0 + wave * 16;

  // Q fragments (B-operand): Q[q=lq][d=lg*8+e], pre-scaled by 0.125 in gemm_qkv
  s16x8 qf[2];
  {
    const bf16* qp = Qg + base + (size_t)(qw0 + lq) * HD_ + lg * 8;
    qf[0] = *(const s16x8*)qp;
    qf[1] = *(const s16x8*)(qp + 32);
  }
  const f32x4 z4 = {0.f, 0.f, 0.f, 0.f};
  f32x4 o[4];
#pragma unroll
  for (int nf = 0; nf < 4; ++nf) o[nf] = z4;
  float mrow = -1e30f, lrow = 0.f;

  const int n_kv = (qt0 + 63) / 128 + 1;
  for (int kt = 0; kt < n_kv; ++kt) {
    const int k0 = kt * 128;
    // stage K: global_load_lds, linear LDS dest + inverse-swizzled global source
#pragma unroll
    for (int i = 0; i < 4; ++i) {
      const int c = tid + i * 256;
      const int key = c >> 3;
      const int s8 = (c & 7) ^ (key & 7);
      gld16(Kg + base + (size_t)(k0 + key) * HD_ + s8 * 8, (char*)Ks + c * 16);
    }
    // V -> regs (T14 issue-early; ds_write after the barrier)
    const int key0 = (tid & 31) * 4, hdg = tid >> 5;
    s16x8 v0, v1, v2, v3;
    {
      const bf16* vp = Vg + base + (size_t)(k0 + key0) * HD_ + hdg * 8;
      v0 = *(const s16x8*)vp;
      v1 = *(const s16x8*)(vp + HD_);
      v2 = *(const s16x8*)(vp + 2 * HD_);
      v3 = *(const s16x8*)(vp + 3 * HD_);
    }
    __syncthreads();   // B1: K in LDS, V in regs; all waves past prior PV
    // V transposed write (overlaps with QK below across waves)
#pragma unroll
    for (int j = 0; j < 8; ++j) {
      const int hd = hdg * 8 + j;
      const int byte = ((hd * 128 + key0) * 2) ^ ((hd & 15) << 4);
      s16x4 wv = { v0[j], v1[j], v2[j], v3[j] };
      *(s16x4*)((char*)Vt + byte) = wv;
    }

    // QK^T swapped: sc[n] = C[key=n*16+lg*4+r][q=lq]
    f32x4 sc[8];
#pragma unroll
    for (int n = 0; n < 8; ++n) sc[n] = z4;
    __builtin_amdgcn_s_setprio(1);
#pragma unroll
    for (int ks = 0; ks < 2; ++ks) {
#pragma unroll
      for (int n = 0; n < 8; ++n) {
        const int key = n * 16 + lq;
        const int byte = (key * 128 + ks * 64 + lg * 16) ^ ((key & 7) << 4);
        const s16x8 kf = *(const s16x8*)((const char*)Ks + byte);
        sc[n] = __builtin_amdgcn_mfma_f32_16x16x32_bf16(kf, qf[ks], sc[n], 0, 0, 0);
      }
    }
    __builtin_amdgcn_s_setprio(0);
    // causal mask: key = k0+n*16+lg*4+r, q = qw0+lq
    if (k0 + 127 > qw0) {
      const int gq = qw0 + lq;
#pragma unroll
      for (int n = 0; n < 8; ++n) {
        const int kb = k0 + n * 16 + lg * 4;
#pragma unroll
        for (int r = 0; r < 4; ++r)
          if (kb + r > gq) sc[n][r] = -1e30f;
      }
    }
    // in-register online softmax (one q-row per lane; 4 lanes redundant per row)
    float mn[8];
#pragma unroll
    for (int n = 0; n < 8; ++n)
      mn[n] = fmaxf(fmaxf(sc[n][0], sc[n][1]), fmaxf(sc[n][2], sc[n][3]));
    float pm = fmaxf(fmaxf(fmaxf(mn[0], mn[1]), fmaxf(mn[2], mn[3])),
                     fmaxf(fmaxf(mn[4], mn[5]), fmaxf(mn[6], mn[7])));
    pm = fmaxf(pm, __shfl_xor(pm, 16, 64));
    pm = fmaxf(pm, __shfl_xor(pm, 32, 64));
    const float mnew = fmaxf(mrow, pm);
    const float alpha = __expf(mrow - mnew);
    mrow = mnew;
    float sn[8];
#pragma unroll
    for (int n = 0; n < 8; ++n) {
#pragma unroll
      for (int r = 0; r < 4; ++r) sc[n][r] = __expf(sc[n][r] - mnew);
      sn[n] = (sc[n][0] + sc[n][1]) + (sc[n][2] + sc[n][3]);
    }
    float rs = ((sn[0] + sn[1]) + (sn[2] + sn[3])) + ((sn[4] + sn[5]) + (sn[6] + sn[7]));
    rs += __shfl_xor(rs, 16, 64);
    rs += __shfl_xor(rs, 32, 64);
    lrow = lrow * alpha + rs;
    // redistribute P^T -> PV B-operand frags: pb[w] = P[q=lq][key=w*32+lg*8+e]
    s16x8 pb[4];
#pragma unroll
    for (int w = 0; w < 4; ++w) {
      const unsigned Aw = pk2(sc[2 * w][0], sc[2 * w][1]);
      const unsigned Bw = pk2(sc[2 * w][2], sc[2 * w][3]);
      const unsigned Cw = pk2(sc[2 * w + 1][0], sc[2 * w + 1][1]);
      const unsigned Dw = pk2(sc[2 * w + 1][2], sc[2 * w + 1][3]);
      const int src0 = lq + ((lg & 1) << 5);
      const int src1 = src0 + 16;
      const unsigned sA0 = __shfl(Aw, src0, 64), sC0 = __shfl(Cw, src0, 64);
      const unsigned sB0 = __shfl(Bw, src0, 64), sD0 = __shfl(Dw, src0, 64);
      const unsigned sA1 = __shfl(Aw, src1, 64), sC1 = __shfl(Cw, src1, 64);
      const unsigned sB1 = __shfl(Bw, src1, 64), sD1 = __shfl(Dw, src1, 64);
      const bool loh = (lg < 2);
      const u32x4 pw = { loh ? sA0 : sC0, loh ? sB0 : sD0,
                         loh ? sA1 : sC1, loh ? sB1 : sD1 };
      pb[w] = __builtin_bit_cast(s16x8, pw);
    }
    // rescale O
#pragma unroll
    for (int nf = 0; nf < 4; ++nf)
#pragma unroll
      for (int r = 0; r < 4; ++r) o[nf][r] *= alpha;
    __syncthreads();   // B2: Vt writes visible; all waves done with Ks reads
    // PV: O^T[hd][q] += V^T[hd][k] P^T[k][q];  A=Vt rows, B=pb
    __builtin_amdgcn_s_setprio(1);
#pragma unroll
    for (int w = 0; w < 4; ++w) {
      const s16x8 pbw = pb[w];
#pragma unroll
      for (int nf = 0; nf < 4; ++nf) {
        const int hd = nf * 16 + lq;
        const int bbyte = ((hd * 128 + w * 32 + lg * 8) * 2) ^ ((hd & 15) << 4);
        const s16x8 vf = *(const s16x8*)((const char*)Vt + bbyte);
        o[nf] = __builtin_amdgcn_mfma_f32_16x16x32_bf16(vf, pbw, o[nf], 0, 0, 0);
      }
    }
    __builtin_amdgcn_s_setprio(0);
  }
  // epilogue: O^T frags: hd = nf*16+lg*4+r, q = lq; 4x b64 stores
  const int b = bh >> 4, h = bh & 15;
  const float rinv = __builtin_amdgcn_rcpf(lrow);
  bf16* cp = ctx + (size_t)(b * S_ + qw0 + lq) * DOUT + h * HD_ + lg * 4;
#pragma unroll
  for (int nf = 0; nf < 4; ++nf) {
    s16x4 ov = { bfbits(o[nf][0] * rinv), bfbits(o[nf][1] * rinv),
                 bfbits(o[nf][2] * rinv), bfbits(o[nf][3] * rinv) };
    *(s16x4*)(cp + nf * 16) = ov;
  }
}

// ---------------- output projection + bias, FLOAT32 out ----------------
__global__ __launch_bounds__(256) void gemm_outproj(
    const bf16* __restrict__ A, const bf16* __restrict__ Wot,
    const float* __restrict__ bo, float* __restrict__ out) {
  __shared__ alignas(16) bf16 Al[128 * 32];
  __shared__ alignas(16) bf16 Bl[128 * 32];
  const int brow = blockIdx.x * 128, bcol = blockIdx.y * 128;
  f32x4 acc[4][4];
  const f32x4 z4 = {0.f, 0.f, 0.f, 0.f};
#pragma unroll
  for (int m = 0; m < 4; ++m)
#pragma unroll
    for (int n = 0; n < 4; ++n) acc[m][n] = z4;
  gemm128_mainloop<1024>(A, Wot, brow, bcol, Al, Bl, acc);
  const int lane = threadIdx.x & 63;
  const int wr = (threadIdx.x >> 6) >> 1, wc = (threadIdx.x >> 6) & 1;
  const int lq = lane & 15, lg = lane >> 4;
#pragma unroll
  for (int m = 0; m < 4; ++m) {
#pragma unroll
    for (int n = 0; n < 4; ++n) {
      const int col = bcol + wc * 64 + n * 16 + lq;
      const float bias = bo[col];
#pragma unroll
      for (int r = 0; r < 4; ++r) {
        const int row = brow + wr * 64 + m * 16 + lg * 4 + r;
        out[(size_t)row * DOUT + col] = acc[m][n][r] + bias;
      }
    }
  }
}

extern "C" void kernel_launch(void* const* d_in, const int* in_sizes, int n_in,
                              void* d_out, int out_size, void* d_ws, size_t ws_size,
                              hipStream_t stream) {
  (void)in_sizes; (void)n_in; (void)out_size; (void)ws_size;
  const float* x  = (const float*)d_in[0];
  const float* Wq = (const float*)d_in[1];
  const float* Wk = (const float*)d_in[2];
  const float* Wv = (const float*)d_in[3];
  const float* Wo = (const float*)d_in[4];
  const float* bo = (const float*)d_in[5];
  float* out = (float*)d_out;

  char* ws = (char*)d_ws;
  bf16* xb  = (bf16*)(ws);                                  // 16 MB: x bf16 [8192][1024]
  bf16* Wqt = (bf16*)(ws + (16u << 20));                    //  2 MB each: Wt[n][k]
  bf16* Wkt = (bf16*)(ws + (18u << 20));
  bf16* Wvt = (bf16*)(ws + (20u << 20));
  bf16* Wot = (bf16*)(ws + (22u << 20));
  bf16* Qb  = (bf16*)(ws + (24u << 20));                    // 16 MB: [b][h][s][hd]
  bf16* Kb  = (bf16*)(ws + (40u << 20));
  bf16* Vb  = (bf16*)(ws + (56u << 20));
  bf16* ctx = (bf16*)(ws + (72u << 20));                    // 16 MB: [b][s][h*64+hd]

  cvt_f32_bf16<<<dim3(8192), dim3(256), 0, stream>>>(x, xb, (B_ * S_ * DIN) / 4);
  transpose_w_bf16<<<dim3(32, 32, 4), dim3(256), 0, stream>>>(Wq, Wk, Wv, Wo,
                                                              Wqt, Wkt, Wvt, Wot);
  gemm_qkv<<<dim3(64, 8, 3), dim3(256), 0, stream>>>(xb, Wqt, Wkt, Wvt, Qb, Kb, Vb);
  attn_fwd<<<dim3(32, 64), dim3(256), 0, stream>>>(Qb, Kb, Vb, ctx);
  gemm_outproj<<<dim3(64, 8), dim3(256), 0, stream>>>(ctx, Wot, bo, out);
}